// Round 12
// baseline (62.062 us; speedup 1.0000x reference)
//
#include <hip/hip_runtime.h>
#include <hip/hip_bf16.h>
#include <stdint.h>

typedef __attribute__((ext_vector_type(8))) __bf16 bf16x8;
typedef __attribute__((ext_vector_type(4))) float f32x4;

static constexpr int Bb = 32, Ss = 512, Dd = 1024, Rr = 256;

__device__ __forceinline__ void gload_lds16(const void* g, void* l) {
  __builtin_amdgcn_global_load_lds(
      (const __attribute__((address_space(1))) void*)g,
      (__attribute__((address_space(3))) void*)l, 16, 0, 0);
}

// ---- prep: Bt[512][1024] bf16. rows 0-255 = L^T, rows 256-511 = R ----------
__global__ __launch_bounds__(256) void prep_kernel(
    const float* __restrict__ L, const float* __restrict__ R,
    __bf16* __restrict__ Bt) {
  int i = blockIdx.x * 256 + threadIdx.x;  // 0 .. 512*1024-1 exactly
  int n = i >> 10;
  int d = i & (Dd - 1);
  float v = (n < Rr) ? L[d * Rr + n] : R[(size_t)(n - Rr) * Dd + d];
  Bt[i] = (__bf16)v;
}

// ---- conv: batchbf = (bf16)batch, 16,777,216 elems, 8 per thread ----------
__global__ __launch_bounds__(256) void conv_kernel(
    const float* __restrict__ batch, __bf16* __restrict__ batchbf) {
  size_t base = ((size_t)blockIdx.x * 256 + threadIdx.x) * 8;
  f32x4 f0 = *(const f32x4*)(batch + base);
  f32x4 f1 = *(const f32x4*)(batch + base + 4);
  bf16x8 v;
  v[0] = (__bf16)f0[0]; v[1] = (__bf16)f0[1];
  v[2] = (__bf16)f0[2]; v[3] = (__bf16)f0[3];
  v[4] = (__bf16)f1[0]; v[5] = (__bf16)f1[1];
  v[6] = (__bf16)f1[2]; v[7] = (__bf16)f1[3];
  *(bf16x8*)(batchbf + base) = v;
}

// ---- stage 1 (preferred): m97-EXACT structure, both operands bf16 ----------
// C[16384,512] = Abf[16384,1024] x Bt[512,1024]^T. 128x128 tile, BK=32,
// 256 thr (4 waves, 2x2 of 64x64), single-buffer 16KB LDS, 2-barrier loop,
// both operands via global_load_lds (2 granules/thread each). Swizzle slot
// g ^ ((row>>1)&3) both sides (2-way residual bank aliasing = free, m136).
__global__ __launch_bounds__(256, 3) void proj_gemm_bf(
    const __bf16* __restrict__ Abf,  // [16384][1024]
    const __bf16* __restrict__ Bt,   // [512][1024]
    __bf16* __restrict__ outL,       // [16384][256]
    __bf16* __restrict__ outR) {     // [16384][256]
  // XCD-chunked (512 = 8*64): per XCD, 16 mt x all 4 nt -> A-panels (4MB)
  // + full B (1MB) resident in that XCD's L2.
  const int s = ((blockIdx.x & 7) << 6) + (blockIdx.x >> 3);
  const int mt = s >> 2;  // 0..127
  const int nt = s & 3;   // 0..3
  const int m0 = mt * 128, n0 = nt * 128;

  __shared__ __align__(16) char smem[16384];
  char* Ab = smem;         // [128][32] bf16, 8KB (4 granules/row)
  char* Bbuf = smem + 8192;

  const int t = threadIdx.x;
  const int lane = t & 63;
  const int wave = t >> 6;
  const int wr = wave >> 1, wc = wave & 1;  // 2x2 waves of 64x64

  f32x4 acc[4][4] = {};

#pragma unroll 1
  for (int it = 0; it < 32; ++it) {
    const int k0 = it * 32;
    __syncthreads();  // prior compute's LDS reads retired
#pragma unroll
    for (int p = 0; p < 2; ++p) {
      int e = p * 256 + t;
      int row = e >> 2, g = e & 3;
      int gs = g ^ ((row >> 1) & 3);  // inverse-swizzled SOURCE, linear dest
      gload_lds16(Abf + (size_t)(m0 + row) * Dd + k0 + gs * 8, Ab + e * 16);
      gload_lds16(Bt + (size_t)(n0 + row) * Dd + k0 + gs * 8, Bbuf + e * 16);
    }
    __syncthreads();  // DMA drained (compiler emits vmcnt(0) before barrier)

    const int g = lane >> 4;  // k-granule 0..3
    bf16x8 a[4], b[4];
#pragma unroll
    for (int m = 0; m < 4; ++m) {
      int row = wr * 64 + m * 16 + (lane & 15);
      a[m] = *(const bf16x8*)(Ab + (row * 4 + (g ^ ((row >> 1) & 3))) * 16);
    }
#pragma unroll
    for (int n = 0; n < 4; ++n) {
      int row = wc * 64 + n * 16 + (lane & 15);
      b[n] = *(const bf16x8*)(Bbuf + (row * 4 + (g ^ ((row >> 1) & 3))) * 16);
    }
#pragma unroll
    for (int m = 0; m < 4; ++m)
#pragma unroll
      for (int n = 0; n < 4; ++n)
        acc[m][n] = __builtin_amdgcn_mfma_f32_16x16x32_bf16(a[m], b[n],
                                                            acc[m][n], 0, 0, 0);
  }

  // epilogue: nt 0-1 -> outL, 2-3 -> outR (C/D: col=lane&15, row=grp*4+i)
  __bf16* out = (n0 < Rr) ? outL : outR;
  const int cb = n0 & (Rr - 1);
  const int col = lane & 15, rgrp = lane >> 4;
#pragma unroll
  for (int m = 0; m < 4; ++m) {
    int r0 = m0 + wr * 64 + m * 16 + rgrp * 4;
#pragma unroll
    for (int n = 0; n < 4; ++n) {
      int c = cb + wc * 64 + n * 16 + col;
#pragma unroll
      for (int i = 0; i < 4; ++i)
        out[(size_t)(r0 + i) * Rr + c] = (__bf16)acc[m][n][i];
    }
  }
}

// ---- stage 1 (fallback, ws too small): R10's passing version --------------
__global__ __launch_bounds__(256, 3) void proj_gemm_f32(
    const float* __restrict__ batch,
    const __bf16* __restrict__ Bt,
    __bf16* __restrict__ outL,
    __bf16* __restrict__ outR) {
  const int s = ((blockIdx.x & 7) << 7) + (blockIdx.x >> 3);
  const int mt = s >> 2;
  const int nt = s & 3;
  const int m0 = mt * 64, n0 = nt * 128;

  __shared__ __align__(16) char smem[49152];
  const int t = threadIdx.x;
  const int lane = t & 63;
  const int wave = t >> 6;
  const int wr = wave >> 1, wc = wave & 1;

  f32x4 acc[2][4] = {};
  f32x4 areg[4];
  const int arow = t >> 2, ag = t & 3;
  const int ags = ag ^ (arow & 7);

  auto issueA = [&](int k0) {
    const float* src = batch + (size_t)(m0 + arow) * Dd + k0 + ag * 8;
    areg[0] = *(const f32x4*)src;
    areg[1] = *(const f32x4*)(src + 4);
    areg[2] = *(const f32x4*)(src + 32);
    areg[3] = *(const f32x4*)(src + 36);
  };
  auto writeA = [&](int buf) {
    char* Ab = smem + buf * 8192;
    bf16x8 v0, v1;
    v0[0] = (__bf16)areg[0][0]; v0[1] = (__bf16)areg[0][1];
    v0[2] = (__bf16)areg[0][2]; v0[3] = (__bf16)areg[0][3];
    v0[4] = (__bf16)areg[1][0]; v0[5] = (__bf16)areg[1][1];
    v0[6] = (__bf16)areg[1][2]; v0[7] = (__bf16)areg[1][3];
    v1[0] = (__bf16)areg[2][0]; v1[1] = (__bf16)areg[2][1];
    v1[2] = (__bf16)areg[2][2]; v1[3] = (__bf16)areg[2][3];
    v1[4] = (__bf16)areg[3][0]; v1[5] = (__bf16)areg[3][1];
    v1[6] = (__bf16)areg[3][2]; v1[7] = (__bf16)areg[3][3];
    *(bf16x8*)(Ab + (arow * 8 + ags) * 16) = v0;
    *(bf16x8*)(Ab + (arow * 8 + (ags ^ 4)) * 16) = v1;
  };
  auto stageB = [&](int buf, int k0) {
    char* Bbuf = smem + 16384 + buf * 16384;
#pragma unroll
    for (int p = 0; p < 4; ++p) {
      int e = p * 256 + t;
      int row = e >> 3, g = e & 7;
      int gs = g ^ (row & 7);
      gload_lds16(Bt + (size_t)(n0 + row) * Dd + k0 + gs * 8, Bbuf + e * 16);
    }
  };
  auto compute = [&](int buf) {
    const char* Ab = smem + buf * 8192;
    const char* Bbuf = smem + 16384 + buf * 16384;
#pragma unroll
    for (int kk = 0; kk < 2; ++kk) {
      const int g = kk * 4 + (lane >> 4);
      bf16x8 a[2], b[4];
#pragma unroll
      for (int m = 0; m < 2; ++m) {
        int row = wr * 32 + m * 16 + (lane & 15);
        a[m] = *(const bf16x8*)(Ab + (row * 8 + (g ^ (row & 7))) * 16);
      }
#pragma unroll
      for (int n = 0; n < 4; ++n) {
        int row = wc * 64 + n * 16 + (lane & 15);
        b[n] = *(const bf16x8*)(Bbuf + (row * 8 + (g ^ (row & 7))) * 16);
      }
#pragma unroll
      for (int m = 0; m < 2; ++m)
#pragma unroll
        for (int n = 0; n < 4; ++n)
          acc[m][n] = __builtin_amdgcn_mfma_f32_16x16x32_bf16(a[m], b[n],
                                                              acc[m][n], 0, 0, 0);
    }
  };

  issueA(0);
  stageB(0, 0);
  writeA(0);
  __syncthreads();
#pragma unroll 1
  for (int tt = 0; tt < 16; ++tt) {
    const int buf = tt & 1;
    if (tt < 15) {
      issueA(tt * 64 + 64);
      stageB(buf ^ 1, tt * 64 + 64);
    }
    compute(buf);
    if (tt < 15) writeA(buf ^ 1);
    __syncthreads();
  }

  __bf16* out = (n0 < Rr) ? outL : outR;
  const int cb = n0 & (Rr - 1);
  const int col = lane & 15, rgrp = lane >> 4;
#pragma unroll
  for (int m = 0; m < 2; ++m) {
    int r0 = m0 + wr * 32 + m * 16 + rgrp * 4;
#pragma unroll
    for (int n = 0; n < 4; ++n) {
      int c = cb + wc * 64 + n * 16 + col;
#pragma unroll
      for (int i = 0; i < 4; ++i)
        out[(size_t)(r0 + i) * Rr + c] = (__bf16)acc[m][n][i];
    }
  }
}

// ---- stage 2: logits[b] = left[b] @ right[b]^T + bias ----------------------
// 64x128 tile, BK=64, single-buffer 24KB, swizzled. 1024 blocks (4/CU).
__global__ __launch_bounds__(256, 4) void score_gemm(
    const __bf16* __restrict__ left,
    const __bf16* __restrict__ right,
    const float* __restrict__ biasp,
    float* __restrict__ out) {
  const int nt = blockIdx.x;  // 0..3
  const int mt = blockIdx.y;  // 0..7
  const int bz = blockIdx.z;  // 0..31
  const __bf16* A = left + (size_t)bz * Ss * Rr;
  const __bf16* B = right + (size_t)bz * Ss * Rr;
  float* O = out + (size_t)bz * Ss * Ss;
  const int m0 = mt * 64, n0 = nt * 128;

  __shared__ __align__(16) char smem[24576];
  const int t = threadIdx.x;
  const int lane = t & 63;
  const int wave = t >> 6;
  const int wr = wave >> 1, wc = wave & 1;

  f32x4 acc[2][4] = {};

  for (int it = 0; it < 4; ++it) {
    const int k0 = it * 64;
    __syncthreads();
#pragma unroll
    for (int q = 0; q < 2; ++q) {
      int e = q * 256 + t;
      int row = e >> 3, g = e & 7;
      int gsrc = g ^ (row & 7);
      gload_lds16(A + (size_t)(m0 + row) * Rr + k0 + gsrc * 8, smem + e * 16);
    }
#pragma unroll
    for (int q = 0; q < 4; ++q) {
      int e = q * 256 + t;
      int row = e >> 3, g = e & 7;
      int gsrc = g ^ (row & 7);
      gload_lds16(B + (size_t)(n0 + row) * Rr + k0 + gsrc * 8,
                  smem + 8192 + e * 16);
    }
    __syncthreads();

#pragma unroll
    for (int kk = 0; kk < 2; ++kk) {
      bf16x8 a[2], b[4];
#pragma unroll
      for (int m = 0; m < 2; ++m) {
        int row = wr * 32 + m * 16 + (lane & 15);
        int g = kk * 4 + (lane >> 4);
        a[m] = *(const bf16x8*)(smem + (row * 8 + (g ^ (row & 7))) * 16);
      }
#pragma unroll
      for (int n = 0; n < 4; ++n) {
        int row = wc * 64 + n * 16 + (lane & 15);
        int g = kk * 4 + (lane >> 4);
        b[n] = *(const bf16x8*)(smem + 8192 +
                                (row * 8 + (g ^ (row & 7))) * 16);
      }
#pragma unroll
      for (int m = 0; m < 2; ++m)
#pragma unroll
        for (int n = 0; n < 4; ++n)
          acc[m][n] = __builtin_amdgcn_mfma_f32_16x16x32_bf16(a[m], b[n],
                                                              acc[m][n], 0, 0, 0);
    }
  }

  const float bias = *biasp;
  const int col = lane & 15, rgrp = lane >> 4;
#pragma unroll
  for (int m = 0; m < 2; ++m) {
    int r0 = m0 + wr * 32 + m * 16 + rgrp * 4;
#pragma unroll
    for (int n = 0; n < 4; ++n) {
      int c = n0 + wc * 64 + n * 16 + col;
#pragma unroll
      for (int i = 0; i < 4; ++i)
        O[(size_t)(r0 + i) * Ss + c] = acc[m][n][i] + bias;
    }
  }
}

extern "C" void kernel_launch(void* const* d_in, const int* in_sizes, int n_in,
                              void* d_out, int out_size, void* d_ws,
                              size_t ws_size, hipStream_t stream) {
  const float* batch = (const float*)d_in[0];  // [32][512][1024]
  const float* projL = (const float*)d_in[1];  // [1024][256]
  const float* projR = (const float*)d_in[2];  // [256][1024]
  const float* bias = (const float*)d_in[3];   // [1]
  float* out = (float*)d_out;                  // [32][512][512]

  char* ws = (char*)d_ws;
  __bf16* left = (__bf16*)(ws);                  // 8,388,608 B [16384][256]
  __bf16* right = (__bf16*)(ws + 8388608);       // 8,388,608 B [16384][256]
  __bf16* Btc = (__bf16*)(ws + 16777216);        // 1,048,576 B [512][1024]
  __bf16* batchbf = (__bf16*)(ws + 17825792);    // 33,554,432 B [16384][1024]
  const size_t WS_NEED = 17825792ull + 33554432ull;  // 51,380,224

  prep_kernel<<<dim3(2048), dim3(256), 0, stream>>>(projL, projR, Btc);
  if (ws_size >= WS_NEED) {
    conv_kernel<<<dim3(8192), dim3(256), 0, stream>>>(batch, batchbf);
    proj_gemm_bf<<<dim3(512), dim3(256), 0, stream>>>(batchbf, Btc, left,
                                                      right);
  } else {
    proj_gemm_f32<<<dim3(1024), dim3(256), 0, stream>>>(batch, Btc, left,
                                                        right);
  }
  score_gemm<<<dim3(4, 8, 32), dim3(256), 0, stream>>>(left, right, bias, out);
}